// Round 5
// baseline (1203.229 us; speedup 1.0000x reference)
//
#include <hip/hip_runtime.h>
#include <hip/hip_bf16.h>
#include <stdint.h>
#include <stddef.h>

// Dims (fixed for this problem)
// B=4096 L=64 H=512 E=256 T=256 S=128 CT=259 R=4096 V=256 IN=1670
// x layout: [a_tm1(256) | p_t(768) | n_t(128) | ctx_env(259) | ctx_lc(259)] = 1670, padded to 1696
#define XP 1696
#define KC 288   // CT=259 padded to 9*32

typedef __attribute__((ext_vector_type(8))) short bf16x8;
typedef __attribute__((ext_vector_type(4))) float f32x4;

__device__ __forceinline__ unsigned short f32_bf16(float f) {
    union { float f; unsigned int u; } v; v.f = f;
    unsigned int r = v.u + 0x7FFFu + ((v.u >> 16) & 1u);
    return (unsigned short)(r >> 16);
}
__device__ __forceinline__ float bf16_f32(unsigned short u) {
    union { unsigned int u; float f; } v; v.u = ((unsigned int)u) << 16;
    return v.f;
}

// ---------------- pack: dst[n][k] = bf16(src[k][n]), k>=Ksrc -> 0 ----------------
__global__ void tpack_kernel(const float* __restrict__ src, unsigned short* __restrict__ dst,
                             int Ksrc, int Nsrc, int Kp, long total) {
    long idx = (long)blockIdx.x * blockDim.x + threadIdx.x;
    if (idx >= total) return;
    int k = (int)(idx / Nsrc);
    int n = (int)(idx - (long)k * Nsrc);
    float v = (k < Ksrc) ? src[(size_t)k * Nsrc + n] : 0.0f;
    dst[(size_t)n * Kp + k] = f32_bf16(v);
}

__global__ void cvt_kernel(const float* __restrict__ src, unsigned short* __restrict__ dst, int total) {
    int idx = blockIdx.x * blockDim.x + threadIdx.x;
    if (idx < total) dst[idx] = f32_bf16(src[idx]);
}

// x base assembly: a_tm1 | p_t | n_t gather | (ctx written later) | zero pad
__global__ void xasm_kernel(const float* __restrict__ a_tm1, const float* __restrict__ p_t,
                            const int* __restrict__ sym, const float* __restrict__ symtab,
                            unsigned short* __restrict__ x_out) {
    int idx = blockIdx.x * blockDim.x + threadIdx.x;
    if (idx >= 4096 * XP) return;
    int b = idx / XP, c = idx - b * XP;
    float v;
    if (c < 256)       v = a_tm1[(size_t)b * 256 + c];
    else if (c < 1024) v = p_t[(size_t)b * 768 + (c - 256)];
    else if (c < 1152) v = symtab[(size_t)sym[b] * 128 + (c - 1024)];
    else if (c < 1670) return;           // ctx slices written by ctx_kernel
    else v = 0.0f;                        // pad 1670..1695
    x_out[idx] = f32_bf16(v);
}

// ---------------- generic GEMM: C[M,N] = act(A[M,K]bf16 @ BT[N,K]bf16^T + bias) ----------------
// m97 structure: 128x128 tile, 4 waves (2x2), wave-tile 64x64, K step 32,
// global_load_lds width-16 staging into LINEAR LDS [128][32] (no VGPR round-trip).
template<int ACT, int OUT_BF16>   // ACT: 0 none, 1 tanh
__global__ __launch_bounds__(256, 2)
void gemm_bt_kernel(const unsigned short* __restrict__ A,
                    const unsigned short* __restrict__ BT,
                    const float* __restrict__ bias,
                    void* __restrict__ Cout,
                    int M, int N, int K)
{
    __shared__ unsigned short a_lds[128 * 32];   // linear: row r at r*32, 64B rows
    __shared__ unsigned short b_lds[128 * 32];
    const int tid  = threadIdx.x;
    const int lane = tid & 63;
    const int wave = tid >> 6;
    const int wm = wave >> 1, wn = wave & 1;
    const int row0 = blockIdx.y * 128;
    const int col0 = blockIdx.x * 128;

    f32x4 acc[4][4];
    #pragma unroll
    for (int i = 0; i < 4; i++)
        #pragma unroll
        for (int j = 0; j < 4; j++) acc[i][j] = (f32x4){0.f, 0.f, 0.f, 0.f};

    const int fr = lane & 15;
    const int kk = (lane >> 4) * 8;
    const int srow = (lane >> 2);        // 0..15
    const int scol = (lane & 3) * 8;     // 0,8,16,24

    for (int k0 = 0; k0 < K; k0 += 32) {
        __syncthreads();   // previous iteration's LDS reads done
        #pragma unroll
        for (int j = 0; j < 4; j++) {
            const int c = (wave & 1) * 4 + j;      // chunk 0..7
            const unsigned short* gsrc;
            unsigned short* ldst;
            if (wave < 2) {
                gsrc = A  + (size_t)(row0 + c * 16 + srow) * K + k0 + scol;
                ldst = &a_lds[c * 512];
            } else {
                gsrc = BT + (size_t)(col0 + c * 16 + srow) * K + k0 + scol;
                ldst = &b_lds[c * 512];
            }
            __builtin_amdgcn_global_load_lds(
                (const __attribute__((address_space(1))) void*)gsrc,
                (__attribute__((address_space(3))) void*)ldst, 16, 0, 0);
        }
        __syncthreads();   // vmcnt drained by barrier semantics

        bf16x8 af[4], bf[4];
        #pragma unroll
        for (int mt = 0; mt < 4; mt++) af[mt] = *(const bf16x8*)&a_lds[(wm * 64 + mt * 16 + fr) * 32 + kk];
        #pragma unroll
        for (int nt = 0; nt < 4; nt++) bf[nt] = *(const bf16x8*)&b_lds[(wn * 64 + nt * 16 + fr) * 32 + kk];
        #pragma unroll
        for (int mt = 0; mt < 4; mt++)
            #pragma unroll
            for (int nt = 0; nt < 4; nt++)
                acc[mt][nt] = __builtin_amdgcn_mfma_f32_16x16x32_bf16(af[mt], bf[nt], acc[mt][nt], 0, 0, 0);
    }

    const int fq = lane >> 4;
    #pragma unroll
    for (int mt = 0; mt < 4; mt++)
        #pragma unroll
        for (int nt = 0; nt < 4; nt++) {
            int cg = col0 + wn * 64 + nt * 16 + fr;
            float bv = bias ? bias[cg] : 0.0f;
            #pragma unroll
            for (int i = 0; i < 4; i++) {
                int rg = row0 + wm * 64 + mt * 16 + fq * 4 + i;
                float v = acc[mt][nt][i] + bv;
                if (ACT == 1) v = tanhf(v);
                if (OUT_BF16) ((unsigned short*)Cout)[(size_t)rg * N + cg] = f32_bf16(v);
                else          ((float*)Cout)[(size_t)rg * N + cg] = v;
            }
        }
}

// ---------------- fused context read (v5: persistent WGs, W1eT in registers) ----------------
// 512 WGs grid-stride 8192 (b,which) items. Each wave loads its 36 W1eT fragments
// (144 VGPR) ONCE -> L2 traffic for W1eT drops 16x and the per-item MFMA phase has
// zero global loads. launch_bounds(512,2) -> 256 VGPR cap so bfr + stage batch stay live.
__global__ __launch_bounds__(512, 2)
void ctx_kernel(const float* __restrict__ emb_env, const float* __restrict__ emb_lc,
                const int* __restrict__ len_env, const int* __restrict__ len_lc,
                const float* __restrict__ s_proj,          // [B,512] f32 (b1 included)
                const unsigned short* __restrict__ W1eT,   // [512][288] bf16 (zero-padded k>=259)
                const float* __restrict__ W2, const float* __restrict__ b2,
                unsigned short* __restrict__ x_out)        // [B][1696] bf16
{
    const int tid = threadIdx.x;   // 0..511
    const int lane = tid & 63;
    const int wave = tid >> 6;     // 0..7, n-slice: wave*64
    const int fr = lane & 15;
    const int fq = lane >> 4;

    __shared__ unsigned short emb_lds[64][296];
    __shared__ float partial_lds[8][64];
    __shared__ float w_lds[64];

    // ---- load this wave's W1eT fragments once (persist in registers) ----
    bf16x8 bfr[9][4];
    #pragma unroll
    for (int ks = 0; ks < 9; ks++)
        #pragma unroll
        for (int nt = 0; nt < 4; nt++) {
            int n = wave * 64 + nt * 16 + fr;
            bfr[ks][nt] = *(const bf16x8*)(W1eT + (size_t)n * KC + ks * 32 + fq * 8);
        }
    float wv[4];
    #pragma unroll
    for (int nt = 0; nt < 4; nt++) wv[nt] = W2[wave * 64 + nt * 16 + fr];
    const float b2v = b2[0];

    // zero pad cols 259..295 once; stage never writes them, so they stay zero
    for (int q = tid; q < 64 * 37; q += 512) {
        int r = q / 37, c = 259 + (q - r * 37);
        emb_lds[r][c] = 0;
    }
    __syncthreads();

    for (int it = blockIdx.x; it < 8192; it += gridDim.x) {
        const int b = it >> 1;
        const int which = it & 1;
        const int len = (which ? len_lc : len_env)[b];
        const int xoff = which ? 1411 : 1152;

        if (len == 0) {   // WG-uniform: default context = 0
            for (int c = tid; c < 259; c += 512)
                x_out[(size_t)b * XP + xoff + c] = 0;
            continue;
        }

        const float* emb = (which ? emb_lc : emb_env) + (size_t)b * (64 * 259);
        const int mtiles = (len + 15) >> 4;          // 1..4 live M-tiles

        // ---- batched stage: all loads issued together, then cvt+store ----
        {
            const int nf4 = (len * 259 + 3) >> 2;    // float4 count (<=4144)
            const float4* emb4 = reinterpret_cast<const float4*>(emb);
            float4 v[9];
            #pragma unroll
            for (int j = 0; j < 9; j++) {
                int q = tid + j * 512;
                if (q < nf4) v[j] = emb4[q];
            }
            #pragma unroll
            for (int j = 0; j < 9; j++) {
                int q = tid + j * 512;
                if (q < nf4) {
                    float fv[4] = {v[j].x, v[j].y, v[j].z, v[j].w};
                    int e0 = q * 4;
                    #pragma unroll
                    for (int jj = 0; jj < 4; jj++) {
                        int e = e0 + jj;           // < 64*259 always
                        int r = e / 259;
                        int c = e - r * 259;
                        emb_lds[r][c] = f32_bf16(fv[jj]);
                    }
                }
            }
        }
        __syncthreads();

        // ---- MFMA: emb_lds x bfr (registers), no global loads ----
        f32x4 acc[4][4];                     // [mt][nt]
        #pragma unroll
        for (int i = 0; i < 4; i++)
            #pragma unroll
            for (int j = 0; j < 4; j++) acc[i][j] = (f32x4){0.f, 0.f, 0.f, 0.f};

        #pragma unroll
        for (int ks = 0; ks < 9; ks++) {
            bf16x8 af[4];
            #pragma unroll
            for (int mt = 0; mt < 4; mt++)
                if (mt < mtiles)
                    af[mt] = *(const bf16x8*)&emb_lds[mt * 16 + fr][ks * 32 + fq * 8];
            __builtin_amdgcn_s_setprio(1);
            #pragma unroll
            for (int nt = 0; nt < 4; nt++)
                #pragma unroll
                for (int mt = 0; mt < 4; mt++)
                    if (mt < mtiles)
                        acc[mt][nt] = __builtin_amdgcn_mfma_f32_16x16x32_bf16(af[mt], bfr[ks][nt], acc[mt][nt], 0, 0, 0);
            __builtin_amdgcn_s_setprio(0);
        }

        // logit partials: relu(acc + s_proj) * W2, reduced over this wave's 64 n's
        float plog[4][4];
        #pragma unroll
        for (int mt = 0; mt < 4; mt++)
            #pragma unroll
            for (int ii = 0; ii < 4; ii++) plog[mt][ii] = 0.f;
        #pragma unroll
        for (int nt = 0; nt < 4; nt++) {
            int n = wave * 64 + nt * 16 + fr;
            float sp = s_proj[(size_t)b * 512 + n];   // L2-hot scalar loads
            #pragma unroll
            for (int mt = 0; mt < 4; mt++)
                if (mt < mtiles)
                    #pragma unroll
                    for (int ii = 0; ii < 4; ii++) {
                        float h = acc[mt][nt][ii] + sp;
                        h = fmaxf(h, 0.f);
                        plog[mt][ii] += h * wv[nt];
                    }
        }
        #pragma unroll
        for (int mt = 0; mt < 4; mt++)
            if (mt < mtiles)
                #pragma unroll
                for (int ii = 0; ii < 4; ii++) {
                    float v = plog[mt][ii];
                    v += __shfl_xor(v, 1); v += __shfl_xor(v, 2);
                    v += __shfl_xor(v, 4); v += __shfl_xor(v, 8);
                    if (fr == 0) partial_lds[wave][mt * 16 + fq * 4 + ii] = v;
                }
        __syncthreads();

        // softmax over L=64 (first wave). logits for l>=len masked (stale partials safe).
        if (tid < 64) {
            float logit;
            if (tid < len) {
                logit = b2v;
                #pragma unroll
                for (int w = 0; w < 8; w++) logit += partial_lds[w][tid];
            } else {
                logit = -1e9f;
            }
            float m = logit;
            #pragma unroll
            for (int off = 1; off < 64; off <<= 1) m = fmaxf(m, __shfl_xor(m, off));
            float e = __expf(logit - m);
            float s = e;
            #pragma unroll
            for (int off = 1; off < 64; off <<= 1) s += __shfl_xor(s, off);
            w_lds[tid] = e / s;
        }
        __syncthreads();

        // ctx[c] = sum_{l<len} w[l] * emb[l][c], 4-way split accumulators
        if (tid < 259) {
            const int c = tid;
            float a0 = 0.f, a1 = 0.f, a2 = 0.f, a3 = 0.f;
            int l = 0;
            for (; l + 3 < len; l += 4) {
                a0 += w_lds[l]     * bf16_f32(emb_lds[l][c]);
                a1 += w_lds[l + 1] * bf16_f32(emb_lds[l + 1][c]);
                a2 += w_lds[l + 2] * bf16_f32(emb_lds[l + 2][c]);
                a3 += w_lds[l + 3] * bf16_f32(emb_lds[l + 3][c]);
            }
            for (; l < len; l++) a0 += w_lds[l] * bf16_f32(emb_lds[l][c]);
            x_out[(size_t)b * XP + xoff + c] = f32_bf16((a0 + a1) + (a2 + a3));
        }
        __syncthreads();   // emb_lds/w_lds reused next item
    }
}

// ---------------- GRU pointwise ----------------
__global__ void gru_kernel(const float* __restrict__ gx, const float* __restrict__ gh,
                           const float* __restrict__ s, unsigned short* __restrict__ h_b) {
    int idx = blockIdx.x * blockDim.x + threadIdx.x;
    if (idx >= 4096 * 512) return;
    int b = idx >> 9, c = idx & 511;
    const float* gxb = gx + (size_t)b * 1536;
    const float* ghb = gh + (size_t)b * 1536;
    float xr = gxb[c], xz = gxb[c + 512], xn = gxb[c + 1024];
    float hr = ghb[c], hz = ghb[c + 512], hn = ghb[c + 1024];
    float r = 1.f / (1.f + __expf(-(xr + hr)));
    float z = 1.f / (1.f + __expf(-(xz + hz)));
    float n = tanhf(xn + r * hn);
    float h = (1.f - z) * n + z * s[idx];
    h_b[idx] = f32_bf16(h);
}

// ---------------- host ----------------
extern "C" void kernel_launch(void* const* d_in, const int* in_sizes, int n_in,
                              void* d_out, int out_size, void* d_ws, size_t ws_size,
                              hipStream_t stream) {
    const float* s_tm1   = (const float*)d_in[0];
    const float* a_tm1   = (const float*)d_in[1];
    const float* p_t     = (const float*)d_in[2];
    const int*   sym     = (const int*)d_in[3];
    const float* env_emb = (const float*)d_in[4];
    const int*   env_len = (const int*)d_in[5];
    const float* lc_emb  = (const float*)d_in[6];
    const int*   lc_len  = (const int*)d_in[7];
    const float* symtab  = (const float*)d_in[8];
    const float* W1      = (const float*)d_in[9];
    const float* b1      = (const float*)d_in[10];
    const float* W2      = (const float*)d_in[11];
    const float* b2      = (const float*)d_in[12];
    const float* W_ih    = (const float*)d_in[13];
    const float* W_hh    = (const float*)d_in[14];
    const float* b_ih    = (const float*)d_in[15];
    const float* b_hh    = (const float*)d_in[16];
    const float* Wd      = (const float*)d_in[17];
    const float* bd      = (const float*)d_in[18];
    const float* rule    = (const float*)d_in[19];

    // ws layout (~42.7 MB)
    char* w = (char*)d_ws;
    float* s_proj = (float*)w;              w += (size_t)4096 * 512 * 4;
    unsigned short* W1sT  = (unsigned short*)w; w += (size_t)512 * 512 * 2;
    unsigned short* W1eT  = (unsigned short*)w; w += (size_t)512 * KC * 2;
    unsigned short* WihT  = (unsigned short*)w; w += (size_t)1536 * XP * 2;
    unsigned short* WhhT  = (unsigned short*)w; w += (size_t)1536 * 512 * 2;
    unsigned short* WdT   = (unsigned short*)w; w += (size_t)256 * 512 * 2;
    unsigned short* ruleb = (unsigned short*)w; w += (size_t)4096 * 256 * 2;
    unsigned short* s_b   = (unsigned short*)w; w += (size_t)4096 * 512 * 2;
    unsigned short* x_b   = (unsigned short*)w; w += (size_t)4096 * XP * 2;
    unsigned short* h_b   = (unsigned short*)w; w += (size_t)4096 * 512 * 2;
    unsigned short* dec_b = (unsigned short*)w; w += (size_t)4096 * 256 * 2;

    // d_out doubles as scratch for gx/gh (consumed before final logits write)
    float* out_f = (float*)d_out;
    float* gx = out_f;                        // [4096][1536]
    float* gh = out_f + (size_t)4096 * 1536;  // [4096][1536]

    // --- packs ---
    tpack_kernel<<<(512 * 512 + 255) / 256, 256, 0, stream>>>(W1, W1sT, 512, 512, 512, (long)512 * 512);
    tpack_kernel<<<(512 * KC + 255) / 256, 256, 0, stream>>>(W1 + (size_t)512 * 512, W1eT, 259, 512, KC, (long)512 * KC);
    tpack_kernel<<<(1536 * XP + 255) / 256, 256, 0, stream>>>(W_ih, WihT, 1670, 1536, XP, (long)1536 * XP);
    tpack_kernel<<<(1536 * 512 + 255) / 256, 256, 0, stream>>>(W_hh, WhhT, 512, 1536, 512, (long)1536 * 512);
    tpack_kernel<<<(256 * 512 + 255) / 256, 256, 0, stream>>>(Wd, WdT, 512, 256, 512, (long)256 * 512);
    cvt_kernel<<<4096, 256, 0, stream>>>(rule, ruleb, 4096 * 256);
    cvt_kernel<<<8192, 256, 0, stream>>>(s_tm1, s_b, 4096 * 512);
    xasm_kernel<<<(4096 * XP + 255) / 256, 256, 0, stream>>>(a_tm1, p_t, sym, symtab, x_b);

    // s_proj = s_tm1 @ W1[:512] + b1
    gemm_bt_kernel<0, 0><<<dim3(4, 32), 256, 0, stream>>>(s_b, W1sT, b1, s_proj, 4096, 512, 512);

    // fused context reads -> x slices (512 persistent WGs, grid-stride over 8192 items)
    ctx_kernel<<<512, 512, 0, stream>>>(env_emb, lc_emb, env_len, lc_len,
                                        s_proj, W1eT, W2, b2, x_b);

    // GRU gates
    gemm_bt_kernel<0, 0><<<dim3(12, 32), 256, 0, stream>>>(x_b, WihT, b_ih, gx, 4096, 1536, XP);
    gemm_bt_kernel<0, 0><<<dim3(12, 32), 256, 0, stream>>>(s_b, WhhT, b_hh, gh, 4096, 1536, 512);
    gru_kernel<<<8192, 256, 0, stream>>>(gx, gh, s_tm1, h_b);

    // dec = tanh(h @ Wd + bd)  (bf16 out)
    gemm_bt_kernel<1, 1><<<dim3(2, 32), 256, 0, stream>>>(h_b, WdT, bd, dec_b, 4096, 256, 512);

    // logits = dec @ rule^T  (overwrites all of d_out)
    gemm_bt_kernel<0, 0><<<dim3(32, 32), 256, 0, stream>>>(dec_b, ruleb, nullptr, out_f, 4096, 4096, 256);
}

// Round 6
// 439.121 us; speedup vs baseline: 2.7401x; 2.7401x over previous
//
#include <hip/hip_runtime.h>
#include <hip/hip_bf16.h>
#include <stdint.h>
#include <stddef.h>

// Dims (fixed): B=4096 L=64 H=512 E=256 T=256 S=128 CT=259 R=4096 V=256 IN=1670
// x layout: [a_tm1(256) | p_t(768) | n_t(128) | ctx_env(259) | ctx_lc(259)] = 1670 pad 1696
#define XP 1696
#define KC 288   // CT=259 padded to 9*32

// --- ctx group schedule geometry ---
// buckets: m>=3 -> 1 item/group (8192 groups cap), m==2 -> 2 items/group (4096),
// m==1 -> 4 items/group (2048). 14336 groups x 4 slots = 57344 slot ints + 3 cursors.
#define BIG_G   8192
#define TWO_G   4096
#define ONE_G   2048
#define N_GROUP (BIG_G + TWO_G + ONE_G)
#define N_SLOTI (N_GROUP * 4)

typedef __attribute__((ext_vector_type(8))) short bf16x8;
typedef __attribute__((ext_vector_type(4))) float f32x4;

__device__ __forceinline__ unsigned short f32_bf16(float f) {
    union { float f; unsigned int u; } v; v.f = f;
    unsigned int r = v.u + 0x7FFFu + ((v.u >> 16) & 1u);
    return (unsigned short)(r >> 16);
}
__device__ __forceinline__ float bf16_f32(unsigned short u) {
    union { unsigned int u; float f; } v; v.u = ((unsigned int)u) << 16;
    return v.f;
}

// ---------------- pack: dst[n][k] = bf16(src[k][n]), k>=Ksrc -> 0 ----------------
__global__ void tpack_kernel(const float* __restrict__ src, unsigned short* __restrict__ dst,
                             int Ksrc, int Nsrc, int Kp, long total) {
    long idx = (long)blockIdx.x * blockDim.x + threadIdx.x;
    if (idx >= total) return;
    int k = (int)(idx / Nsrc);
    int n = (int)(idx - (long)k * Nsrc);
    float v = (k < Ksrc) ? src[(size_t)k * Nsrc + n] : 0.0f;
    dst[(size_t)n * Kp + k] = f32_bf16(v);
}

__global__ void cvt_kernel(const float* __restrict__ src, unsigned short* __restrict__ dst, int total) {
    int idx = blockIdx.x * blockDim.x + threadIdx.x;
    if (idx < total) dst[idx] = f32_bf16(src[idx]);
}

// x base assembly: a_tm1 | p_t | n_t gather | (ctx written later) | zero pad
__global__ void xasm_kernel(const float* __restrict__ a_tm1, const float* __restrict__ p_t,
                            const int* __restrict__ sym, const float* __restrict__ symtab,
                            unsigned short* __restrict__ x_out) {
    int idx = blockIdx.x * blockDim.x + threadIdx.x;
    if (idx >= 4096 * XP) return;
    int b = idx / XP, c = idx - b * XP;
    float v;
    if (c < 256)       v = a_tm1[(size_t)b * 256 + c];
    else if (c < 1024) v = p_t[(size_t)b * 768 + (c - 256)];
    else if (c < 1152) v = symtab[(size_t)sym[b] * 128 + (c - 1024)];
    else if (c < 1670) return;           // ctx slices written by ctx_kernel
    else v = 0.0f;                        // pad 1670..1695
    x_out[idx] = f32_bf16(v);
}

// ---------------- ctx schedule: init + build ----------------
__global__ void sinit_kernel(int* __restrict__ s) {
    int i = blockIdx.x * 256 + threadIdx.x;
    if (i < N_SLOTI) s[i] = -1;
    else if (i < N_SLOTI + 3) s[i] = 0;
}

// item idx in [0,8192): b=idx>>1, which=idx&1. m'=max(ceil(len/16),1).
// slot content = idx*4 + tile_index; an item's tiles occupy consecutive slots,
// never crossing a group (4-slot) boundary; head tile has (d&3)==0.
__global__ void sched_kernel(const int* __restrict__ len_env, const int* __restrict__ len_lc,
                             int* __restrict__ slots) {
    int idx = blockIdx.x * blockDim.x + threadIdx.x;
    if (idx >= 8192) return;
    int b = idx >> 1, wh = idx & 1;
    int len = wh ? len_lc[b] : len_env[b];
    int m = (len + 15) >> 4;
    if (m == 0) m = 1;
    if (m > 4) m = 4;
    int* cursors = slots + N_SLOTI;
    int base;
    if (m >= 3)      { int p = atomicAdd(&cursors[0], 1); base = p * 4; }
    else if (m == 2) { int p = atomicAdd(&cursors[1], 1); base = BIG_G * 4 + (p >> 1) * 4 + (p & 1) * 2; }
    else             { int p = atomicAdd(&cursors[2], 1); base = (BIG_G + TWO_G) * 4 + (p >> 2) * 4 + (p & 3); }
    for (int k = 0; k < m; k++) slots[base + k] = idx * 4 + k;
}

// ---------------- generic GEMM: C[M,N] = act(A[M,K]bf16 @ BT[N,K]bf16^T + bias) ----------------
// m97 structure: 128x128 tile, 4 waves (2x2), wave-tile 64x64, K step 32,
// global_load_lds width-16 staging into LINEAR LDS [128][32].
template<int ACT, int OUT_BF16>   // ACT: 0 none, 1 tanh
__global__ __launch_bounds__(256, 2)
void gemm_bt_kernel(const unsigned short* __restrict__ A,
                    const unsigned short* __restrict__ BT,
                    const float* __restrict__ bias,
                    void* __restrict__ Cout,
                    int M, int N, int K)
{
    __shared__ unsigned short a_lds[128 * 32];
    __shared__ unsigned short b_lds[128 * 32];
    const int tid  = threadIdx.x;
    const int lane = tid & 63;
    const int wave = tid >> 6;
    const int wm = wave >> 1, wn = wave & 1;
    const int row0 = blockIdx.y * 128;
    const int col0 = blockIdx.x * 128;

    f32x4 acc[4][4];
    #pragma unroll
    for (int i = 0; i < 4; i++)
        #pragma unroll
        for (int j = 0; j < 4; j++) acc[i][j] = (f32x4){0.f, 0.f, 0.f, 0.f};

    const int fr = lane & 15;
    const int kk = (lane >> 4) * 8;
    const int srow = (lane >> 2);        // 0..15
    const int scol = (lane & 3) * 8;     // 0,8,16,24

    for (int k0 = 0; k0 < K; k0 += 32) {
        __syncthreads();
        #pragma unroll
        for (int j = 0; j < 4; j++) {
            const int c = (wave & 1) * 4 + j;      // chunk 0..7
            const unsigned short* gsrc;
            unsigned short* ldst;
            if (wave < 2) {
                gsrc = A  + (size_t)(row0 + c * 16 + srow) * K + k0 + scol;
                ldst = &a_lds[c * 512];
            } else {
                gsrc = BT + (size_t)(col0 + c * 16 + srow) * K + k0 + scol;
                ldst = &b_lds[c * 512];
            }
            __builtin_amdgcn_global_load_lds(
                (const __attribute__((address_space(1))) void*)gsrc,
                (__attribute__((address_space(3))) void*)ldst, 16, 0, 0);
        }
        __syncthreads();

        bf16x8 af[4], bf[4];
        #pragma unroll
        for (int mt = 0; mt < 4; mt++) af[mt] = *(const bf16x8*)&a_lds[(wm * 64 + mt * 16 + fr) * 32 + kk];
        #pragma unroll
        for (int nt = 0; nt < 4; nt++) bf[nt] = *(const bf16x8*)&b_lds[(wn * 64 + nt * 16 + fr) * 32 + kk];
        #pragma unroll
        for (int mt = 0; mt < 4; mt++)
            #pragma unroll
            for (int nt = 0; nt < 4; nt++)
                acc[mt][nt] = __builtin_amdgcn_mfma_f32_16x16x32_bf16(af[mt], bf[nt], acc[mt][nt], 0, 0, 0);
    }

    const int fq = lane >> 4;
    #pragma unroll
    for (int mt = 0; mt < 4; mt++)
        #pragma unroll
        for (int nt = 0; nt < 4; nt++) {
            int cg = col0 + wn * 64 + nt * 16 + fr;
            float bv = bias ? bias[cg] : 0.0f;
            #pragma unroll
            for (int i = 0; i < 4; i++) {
                int rg = row0 + wm * 64 + mt * 16 + fq * 4 + i;
                float v = acc[mt][nt][i] + bv;
                if (ACT == 1) v = tanhf(v);
                if (OUT_BF16) ((unsigned short*)Cout)[(size_t)rg * N + cg] = f32_bf16(v);
                else          ((float*)Cout)[(size_t)rg * N + cg] = v;
            }
        }
}

// ---------------- fused context read (v6: bin-packed 4-tile groups) ----------------
// One WG per schedule group: 4 M-tile slots, each slot = 16 live rows of some item.
// Items never cross groups; per-item softmax on the wave owning the item's head slot.
__global__ __launch_bounds__(512, 4)
void ctx_kernel(const float* __restrict__ emb_env, const float* __restrict__ emb_lc,
                const int* __restrict__ len_env, const int* __restrict__ len_lc,
                const float* __restrict__ s_proj,          // [B,512] f32 (b1 included)
                const unsigned short* __restrict__ W1eT,   // [512][288] bf16 (zero-padded k>=259)
                const float* __restrict__ W2, const float* __restrict__ b2,
                const int* __restrict__ slots,
                unsigned short* __restrict__ x_out)        // [B][1696] bf16
{
    const int g = blockIdx.x;
    const int4 dv = *reinterpret_cast<const int4*>(slots + (size_t)g * 4);
    if (dv.x < 0) return;                    // group unused (slot 0 always filled first)
    int d[4] = {dv.x, dv.y, dv.z, dv.w};

    __shared__ unsigned short emb_lds[64][296];
    __shared__ float partial_lds[8][64];
    __shared__ float w_lds[64];

    const int tid = threadIdx.x;   // 0..511
    const int lane = tid & 63;
    const int wave = tid >> 6;
    const int fr = lane & 15;
    const int fq = lane >> 4;
    const float b2v = b2[0];

    // ---- stage: 128 threads per slot ----
    {
        const int sl = tid >> 7;             // slot 0..3
        const int t  = tid & 127;
        const int ds = d[sl];
        int nrows = 0;
        const float* src = nullptr;
        if (ds >= 0) {
            int it = ds >> 2, tix = ds & 3;
            int b = it >> 1, wh = it & 1;
            int len = (wh ? len_lc : len_env)[b];
            nrows = len - tix * 16;
            if (nrows > 16) nrows = 16;
            if (nrows < 0) nrows = 0;
            src = (wh ? emb_lc : emb_env) + ((size_t)b * 64 + tix * 16) * 259;
        }
        // zero K-pad cols 259..295 (all 16 rows of this slot)
        for (int q = t; q < 16 * 37; q += 128) {
            int r = q / 37, c = 259 + (q - (q / 37) * 37);
            emb_lds[sl * 16 + r][c] = 0;
        }
        // zero dead rows (cols 0..258)
        const int ndead = (16 - nrows) * 259;
        for (int q = t; q < ndead; q += 128) {
            int r = nrows + q / 259, c = q - (q / 259) * 259;
            emb_lds[sl * 16 + r][c] = 0;
        }
        // batched stage of nrows*259 f32 (flat float4; loads issued together)
        const int nf4 = (nrows * 259 + 3) >> 2;   // <= 1036
        const float4* s4 = reinterpret_cast<const float4*>(src);
        float4 v[9];
        #pragma unroll
        for (int j = 0; j < 9; j++) {
            int q = t + j * 128;
            if (q < nf4) v[j] = s4[q];
        }
        #pragma unroll
        for (int j = 0; j < 9; j++) {
            int q = t + j * 128;
            if (q < nf4) {
                float fv[4] = {v[j].x, v[j].y, v[j].z, v[j].w};
                int e0 = q * 4;
                #pragma unroll
                for (int jj = 0; jj < 4; jj++) {
                    int e = e0 + jj;              // stays within this slot's 16 rows
                    int r = e / 259;
                    int c = e - r * 259;
                    emb_lds[sl * 16 + r][c] = f32_bf16(fv[jj]);
                }
            }
        }
    }
    __syncthreads();

    // ---- MFMA: 4 M-tiles x 4 n-tiles (n-slice 64/wave), K=288 ----
    f32x4 acc[4][4];
    #pragma unroll
    for (int i = 0; i < 4; i++)
        #pragma unroll
        for (int j = 0; j < 4; j++) acc[i][j] = (f32x4){0.f, 0.f, 0.f, 0.f};

    #pragma unroll
    for (int ks = 0; ks < 9; ks++) {
        bf16x8 bfr[4];
        #pragma unroll
        for (int nt = 0; nt < 4; nt++) {
            int n = wave * 64 + nt * 16 + fr;
            bfr[nt] = *(const bf16x8*)(W1eT + (size_t)n * KC + ks * 32 + fq * 8);
        }
        bf16x8 af[4];
        #pragma unroll
        for (int mt = 0; mt < 4; mt++)
            af[mt] = *(const bf16x8*)&emb_lds[mt * 16 + fr][ks * 32 + fq * 8];
        __builtin_amdgcn_s_setprio(1);
        #pragma unroll
        for (int nt = 0; nt < 4; nt++)
            #pragma unroll
            for (int mt = 0; mt < 4; mt++)
                acc[mt][nt] = __builtin_amdgcn_mfma_f32_16x16x32_bf16(af[mt], bfr[nt], acc[mt][nt], 0, 0, 0);
        __builtin_amdgcn_s_setprio(0);
    }

    // ---- epilogue: relu(acc + s_proj[b_of_slot]) * W2, reduce to per-row logit partials ----
    int bslot[4];
    #pragma unroll
    for (int mt = 0; mt < 4; mt++) bslot[mt] = d[mt] >= 0 ? (d[mt] >> 3) : -1;

    float wv[4];
    #pragma unroll
    for (int nt = 0; nt < 4; nt++) wv[nt] = W2[wave * 64 + nt * 16 + fr];

    float plog[4][4];
    #pragma unroll
    for (int mt = 0; mt < 4; mt++)
        #pragma unroll
        for (int ii = 0; ii < 4; ii++) plog[mt][ii] = 0.f;
    #pragma unroll
    for (int nt = 0; nt < 4; nt++) {
        int n = wave * 64 + nt * 16 + fr;
        #pragma unroll
        for (int mt = 0; mt < 4; mt++) {
            if (bslot[mt] < 0) continue;
            float sp = s_proj[(size_t)bslot[mt] * 512 + n];
            #pragma unroll
            for (int ii = 0; ii < 4; ii++) {
                float h = acc[mt][nt][ii] + sp;
                h = fmaxf(h, 0.f);
                plog[mt][ii] += h * wv[nt];
            }
        }
    }
    #pragma unroll
    for (int mt = 0; mt < 4; mt++) {
        if (bslot[mt] < 0) continue;
        #pragma unroll
        for (int ii = 0; ii < 4; ii++) {
            float v = plog[mt][ii];
            v += __shfl_xor(v, 1); v += __shfl_xor(v, 2);
            v += __shfl_xor(v, 4); v += __shfl_xor(v, 8);
            if (fr == 0) partial_lds[wave][mt * 16 + fq * 4 + ii] = v;
        }
    }
    __syncthreads();

    // ---- per-item softmax: wave v handles slot v if it is an item head ----
    if (wave < 4) {
        int dh = d[wave];
        if (dh >= 0 && (dh & 3) == 0) {
            int it = dh >> 2;
            int b = it >> 1, wh = it & 1;
            int len = (wh ? len_lc : len_env)[b];
            int m = (len + 15) >> 4; if (m == 0) m = 1;
            float logit = -1e9f;
            if (lane < 16 * m && lane < len) {
                logit = b2v;
                #pragma unroll
                for (int w = 0; w < 8; w++) logit += partial_lds[w][wave * 16 + lane];
            }
            float mx = logit;
            #pragma unroll
            for (int off = 1; off < 64; off <<= 1) mx = fmaxf(mx, __shfl_xor(mx, off));
            float e = __expf(logit - mx);
            float s = e;
            #pragma unroll
            for (int off = 1; off < 64; off <<= 1) s += __shfl_xor(s, off);
            if (lane < 16 * m) w_lds[wave * 16 + lane] = e / s;
        }
    }
    __syncthreads();

    // ---- wsum per head item: ctx[c] = sum_{l<len} w[l] * emb[l][c] ----
    #pragma unroll
    for (int g4 = 0; g4 < 4; g4++) {
        int dh = d[g4];
        if (dh < 0 || (dh & 3) != 0) continue;
        int it = dh >> 2;
        int b = it >> 1, wh = it & 1;
        int len = (wh ? len_lc : len_env)[b];
        int xoff = wh ? 1411 : 1152;
        if (tid < 259) {
            const int c = tid;
            const int base = g4 * 16;
            float a0 = 0.f, a1 = 0.f, a2 = 0.f, a3 = 0.f;
            int l = 0;
            for (; l + 3 < len; l += 4) {
                a0 += w_lds[base + l]     * bf16_f32(emb_lds[base + l][c]);
                a1 += w_lds[base + l + 1] * bf16_f32(emb_lds[base + l + 1][c]);
                a2 += w_lds[base + l + 2] * bf16_f32(emb_lds[base + l + 2][c]);
                a3 += w_lds[base + l + 3] * bf16_f32(emb_lds[base + l + 3][c]);
            }
            for (; l < len; l++) a0 += w_lds[base + l] * bf16_f32(emb_lds[base + l][c]);
            x_out[(size_t)b * XP + xoff + c] = f32_bf16((a0 + a1) + (a2 + a3));
        }
    }
}

// ---------------- GRU pointwise ----------------
__global__ void gru_kernel(const float* __restrict__ gx, const float* __restrict__ gh,
                           const float* __restrict__ s, unsigned short* __restrict__ h_b) {
    int idx = blockIdx.x * blockDim.x + threadIdx.x;
    if (idx >= 4096 * 512) return;
    int b = idx >> 9, c = idx & 511;
    const float* gxb = gx + (size_t)b * 1536;
    const float* ghb = gh + (size_t)b * 1536;
    float xr = gxb[c], xz = gxb[c + 512], xn = gxb[c + 1024];
    float hr = ghb[c], hz = ghb[c + 512], hn = ghb[c + 1024];
    float r = 1.f / (1.f + __expf(-(xr + hr)));
    float z = 1.f / (1.f + __expf(-(xz + hz)));
    float n = tanhf(xn + r * hn);
    float h = (1.f - z) * n + z * s[idx];
    h_b[idx] = f32_bf16(h);
}

// ---------------- host ----------------
extern "C" void kernel_launch(void* const* d_in, const int* in_sizes, int n_in,
                              void* d_out, int out_size, void* d_ws, size_t ws_size,
                              hipStream_t stream) {
    const float* s_tm1   = (const float*)d_in[0];
    const float* a_tm1   = (const float*)d_in[1];
    const float* p_t     = (const float*)d_in[2];
    const int*   sym     = (const int*)d_in[3];
    const float* env_emb = (const float*)d_in[4];
    const int*   env_len = (const int*)d_in[5];
    const float* lc_emb  = (const float*)d_in[6];
    const int*   lc_len  = (const int*)d_in[7];
    const float* symtab  = (const float*)d_in[8];
    const float* W1      = (const float*)d_in[9];
    const float* b1      = (const float*)d_in[10];
    const float* W2      = (const float*)d_in[11];
    const float* b2      = (const float*)d_in[12];
    const float* W_ih    = (const float*)d_in[13];
    const float* W_hh    = (const float*)d_in[14];
    const float* b_ih    = (const float*)d_in[15];
    const float* b_hh    = (const float*)d_in[16];
    const float* Wd      = (const float*)d_in[17];
    const float* bd      = (const float*)d_in[18];
    const float* rule    = (const float*)d_in[19];

    // ws layout (~43 MB)
    char* w = (char*)d_ws;
    float* s_proj = (float*)w;              w += (size_t)4096 * 512 * 4;
    unsigned short* W1sT  = (unsigned short*)w; w += (size_t)512 * 512 * 2;
    unsigned short* W1eT  = (unsigned short*)w; w += (size_t)512 * KC * 2;
    unsigned short* WihT  = (unsigned short*)w; w += (size_t)1536 * XP * 2;
    unsigned short* WhhT  = (unsigned short*)w; w += (size_t)1536 * 512 * 2;
    unsigned short* WdT   = (unsigned short*)w; w += (size_t)256 * 512 * 2;
    unsigned short* ruleb = (unsigned short*)w; w += (size_t)4096 * 256 * 2;
    unsigned short* s_b   = (unsigned short*)w; w += (size_t)4096 * 512 * 2;
    unsigned short* x_b   = (unsigned short*)w; w += (size_t)4096 * XP * 2;
    unsigned short* h_b   = (unsigned short*)w; w += (size_t)4096 * 512 * 2;
    unsigned short* dec_b = (unsigned short*)w; w += (size_t)4096 * 256 * 2;
    int* slots = (int*)w;                   w += (size_t)(N_SLOTI + 8) * 4;   // +cursors

    // d_out doubles as scratch for gx/gh (consumed before final logits write)
    float* out_f = (float*)d_out;
    float* gx = out_f;                        // [4096][1536]
    float* gh = out_f + (size_t)4096 * 1536;  // [4096][1536]

    // --- schedule init/build (overlaps nothing; tiny) ---
    sinit_kernel<<<(N_SLOTI + 3 + 255) / 256, 256, 0, stream>>>(slots);
    sched_kernel<<<32, 256, 0, stream>>>(env_len, lc_len, slots);

    // --- packs ---
    tpack_kernel<<<(512 * 512 + 255) / 256, 256, 0, stream>>>(W1, W1sT, 512, 512, 512, (long)512 * 512);
    tpack_kernel<<<(512 * KC + 255) / 256, 256, 0, stream>>>(W1 + (size_t)512 * 512, W1eT, 259, 512, KC, (long)512 * KC);
    tpack_kernel<<<(1536 * XP + 255) / 256, 256, 0, stream>>>(W_ih, WihT, 1670, 1536, XP, (long)1536 * XP);
    tpack_kernel<<<(1536 * 512 + 255) / 256, 256, 0, stream>>>(W_hh, WhhT, 512, 1536, 512, (long)1536 * 512);
    tpack_kernel<<<(256 * 512 + 255) / 256, 256, 0, stream>>>(Wd, WdT, 512, 256, 512, (long)256 * 512);
    cvt_kernel<<<4096, 256, 0, stream>>>(rule, ruleb, 4096 * 256);
    cvt_kernel<<<8192, 256, 0, stream>>>(s_tm1, s_b, 4096 * 512);
    xasm_kernel<<<(4096 * XP + 255) / 256, 256, 0, stream>>>(a_tm1, p_t, sym, symtab, x_b);

    // s_proj = s_tm1 @ W1[:512] + b1
    gemm_bt_kernel<0, 0><<<dim3(4, 32), 256, 0, stream>>>(s_b, W1sT, b1, s_proj, 4096, 512, 512);

    // fused context reads -> x slices (bin-packed groups)
    ctx_kernel<<<N_GROUP, 512, 0, stream>>>(env_emb, lc_emb, env_len, lc_len,
                                            s_proj, W1eT, W2, b2, slots, x_b);

    // GRU gates
    gemm_bt_kernel<0, 0><<<dim3(12, 32), 256, 0, stream>>>(x_b, WihT, b_ih, gx, 4096, 1536, XP);
    gemm_bt_kernel<0, 0><<<dim3(12, 32), 256, 0, stream>>>(s_b, WhhT, b_hh, gh, 4096, 1536, 512);
    gru_kernel<<<8192, 256, 0, stream>>>(gx, gh, s_tm1, h_b);

    // dec = tanh(h @ Wd + bd)  (bf16 out)
    gemm_bt_kernel<1, 1><<<dim3(2, 32), 256, 0, stream>>>(h_b, WdT, bd, dec_b, 4096, 256, 512);

    // logits = dec @ rule^T  (overwrites all of d_out)
    gemm_bt_kernel<0, 0><<<dim3(32, 32), 256, 0, stream>>>(dec_b, ruleb, nullptr, out_f, 4096, 4096, 256);
}